// Round 1
// baseline (375.262 us; speedup 1.0000x reference)
//
#include <hip/hip_runtime.h>
#include <cstdint>
#include <cstddef>

typedef float f32x4 __attribute__((ext_vector_type(4)));
typedef __bf16 bf16x8 __attribute__((ext_vector_type(8)));

#define BB 16
#define SEQ 1024
#define DMODEL 768
#define NHEAD 12
#define HDIM 64
#define MTOT (BB * SEQ)
#define NQKV (3 * DMODEL)

static __device__ __forceinline__ unsigned short f2bf(float f) {
  unsigned int u = __builtin_bit_cast(unsigned int, f);
  u += 0x7fffu + ((u >> 16) & 1u);
  return (unsigned short)(u >> 16);
}

static __device__ __forceinline__ void gload_lds16(const void* g, void* l) {
  __builtin_amdgcn_global_load_lds((__attribute__((address_space(1))) void*)g,
                                   (__attribute__((address_space(3))) void*)l,
                                   16, 0, 0);
}

// ---- prep: f32 -> bf16 convert (vectorized) ----
__global__ void k_cvt_bf16(const float4* __restrict__ in, ushort4* __restrict__ out, int n4) {
  int stride = gridDim.x * blockDim.x;
  for (int i = blockIdx.x * blockDim.x + threadIdx.x; i < n4; i += stride) {
    float4 v = in[i];
    ushort4 o;
    o.x = f2bf(v.x); o.y = f2bf(v.y); o.z = f2bf(v.z); o.w = f2bf(v.w);
    out[i] = o;
  }
}

// ---- prep: transpose f32 [R][C] -> bf16 [C][R] ----
__global__ void k_transpose_bf16(const float* __restrict__ in, unsigned short* __restrict__ out,
                                 int R, int C) {
  __shared__ float tile[32][33];
  int tx = threadIdx.x & 31, ty = threadIdx.x >> 5;
  int c0 = blockIdx.x * 32, r0 = blockIdx.y * 32;
#pragma unroll
  for (int i = 0; i < 4; ++i)
    tile[ty + i * 8][tx] = in[(size_t)(r0 + ty + i * 8) * C + c0 + tx];
  __syncthreads();
#pragma unroll
  for (int i = 0; i < 4; ++i)
    out[(size_t)(c0 + ty + i * 8) * R + r0 + tx] = f2bf(tile[tx][ty + i * 8]);
}

// ---- GEMM C[M,N] = A[M,K] * Bt[N,K]^T, bf16 in, f32 accum ----
// MODE 0: outF = C + bias (f32). MODE 1: scatter to Q,K (row-major per head) and V^T.
template <int MODE>
__global__ __launch_bounds__(256) void k_gemm_bt(
    const unsigned short* __restrict__ A, const unsigned short* __restrict__ Bt,
    int M, int N, int K,
    float* __restrict__ outF, const float* __restrict__ bias,
    unsigned short* __restrict__ Qd, unsigned short* __restrict__ Kd,
    unsigned short* __restrict__ Vt) {
  __shared__ __align__(16) unsigned short As[128 * 32];
  __shared__ __align__(16) unsigned short Bs[128 * 32];
  const int tid = threadIdx.x;
  const int lane = tid & 63, wid = tid >> 6;
  const int ln15 = lane & 15, lh = lane >> 4;
  const int wr = wid >> 1, wc = wid & 1;
  const int m0 = blockIdx.y * 128, n0 = blockIdx.x * 128;
  f32x4 acc[4][4] = {};
  const int nk = K >> 5;
  const int srow = lane >> 2;      // row within 16-row chunk
  const int skb = (lane & 3) * 8;  // k element offset within 32

  for (int kt = 0; kt < nk; ++kt) {
    const int k0 = kt * 32;
#pragma unroll
    for (int c2 = 0; c2 < 2; ++c2) {
      const int c = wid * 2 + c2;
      const int row = c * 16 + srow;
      gload_lds16(A + (size_t)(m0 + row) * K + k0 + skb, &As[c * 512]);
      gload_lds16(Bt + (size_t)(n0 + row) * K + k0 + skb, &Bs[c * 512]);
    }
    __syncthreads();
    bf16x8 af[4], bfv[4];
#pragma unroll
    for (int t = 0; t < 4; ++t) {
      af[t]  = *reinterpret_cast<const bf16x8*>(&As[(wr * 64 + t * 16 + ln15) * 32 + lh * 8]);
      bfv[t] = *reinterpret_cast<const bf16x8*>(&Bs[(wc * 64 + t * 16 + ln15) * 32 + lh * 8]);
    }
#pragma unroll
    for (int mt = 0; mt < 4; ++mt)
#pragma unroll
      for (int nt = 0; nt < 4; ++nt)
        acc[mt][nt] = __builtin_amdgcn_mfma_f32_16x16x32_bf16(af[mt], bfv[nt], acc[mt][nt], 0, 0, 0);
    __syncthreads();
  }

#pragma unroll
  for (int mt = 0; mt < 4; ++mt) {
#pragma unroll
    for (int nt = 0; nt < 4; ++nt) {
#pragma unroll
      for (int r = 0; r < 4; ++r) {
        const int m = m0 + wr * 64 + mt * 16 + lh * 4 + r;
        const int n = n0 + wc * 64 + nt * 16 + ln15;
        const float v = acc[mt][nt][r];
        if (MODE == 0) {
          outF[(size_t)m * N + n] = v + bias[n];
        } else {
          const int which = n / DMODEL;
          const int rr = n - which * DMODEL;
          const int h = rr >> 6, d = rr & 63;
          const int b = m >> 10, nr = m & 1023;
          const unsigned short bv = f2bf(v);
          const size_t bh = (size_t)(b * NHEAD + h);
          if (which == 0)      Qd[(bh * SEQ + nr) * HDIM + d] = bv;
          else if (which == 1) Kd[(bh * SEQ + nr) * HDIM + d] = bv;
          else                 Vt[(bh * HDIM + d) * SEQ + nr] = bv;
        }
      }
    }
  }
}

// ---- fused flash-style attention: per block = (b, h, 64 q-rows); 4 waves x 16 rows ----
__global__ __launch_bounds__(256) void k_attn(
    const unsigned short* __restrict__ Qd, const unsigned short* __restrict__ Kd,
    const unsigned short* __restrict__ Vt, unsigned short* __restrict__ O) {
  __shared__ __align__(16) unsigned short Ks[64 * 64];      // [kpos][d]
  __shared__ __align__(16) unsigned short Vs[64 * 64];      // [d][kpos]
  __shared__ __align__(16) unsigned short Ps[4][16 * 72];   // per-wave P [q][kpos], stride 72
  const int tid = threadIdx.x;
  const int lane = tid & 63, w = tid >> 6;
  const int ln15 = lane & 15, lh = lane >> 4;
  const int bid = blockIdx.x;
  const int qb = bid & 15;
  const int h = (bid >> 4) % NHEAD;
  const int b = bid / (16 * NHEAD);
  const size_t bh = (size_t)(b * NHEAD + h);
  const unsigned short* Qbase = Qd + (bh * SEQ + (size_t)qb * 64 + w * 16) * HDIM;
  const unsigned short* Kbase = Kd + bh * SEQ * HDIM;
  const unsigned short* Vbase = Vt + bh * HDIM * SEQ;

  bf16x8 aq[2];
#pragma unroll
  for (int ch = 0; ch < 2; ++ch)
    aq[ch] = *reinterpret_cast<const bf16x8*>(Qbase + (size_t)ln15 * HDIM + ch * 32 + lh * 8);

  f32x4 acc[4] = {};
  float mr[4], lr[4];
#pragma unroll
  for (int r = 0; r < 4; ++r) { mr[r] = -1e30f; lr[r] = 0.f; }

  for (int kb = 0; kb < SEQ / 64; ++kb) {
    const unsigned short* Kt = Kbase + (size_t)kb * 64 * HDIM;  // contiguous 64x64 tile
#pragma unroll
    for (int c2 = 0; c2 < 2; ++c2) {
      const int c = w * 2 + c2;
      gload_lds16(Kt + c * 512 + lane * 8, &Ks[c * 512]);
      const int d = c * 8 + (lane >> 3);
      const int kp = (lane & 7) * 8;
      gload_lds16(Vbase + (size_t)d * SEQ + kb * 64 + kp, &Vs[c * 512]);
    }
    __syncthreads();

    // S = Q K^T * scale
    f32x4 s[4] = {};
#pragma unroll
    for (int t = 0; t < 4; ++t) {
#pragma unroll
      for (int ch = 0; ch < 2; ++ch) {
        bf16x8 bk = *reinterpret_cast<const bf16x8*>(&Ks[(t * 16 + ln15) * 64 + ch * 32 + lh * 8]);
        s[t] = __builtin_amdgcn_mfma_f32_16x16x32_bf16(aq[ch], bk, s[t], 0, 0, 0);
      }
    }
#pragma unroll
    for (int t = 0; t < 4; ++t) s[t] *= 0.125f;

    // online softmax (rows live on reg index; row-reduce across 16 lanes of group)
    float al[4];
#pragma unroll
    for (int r = 0; r < 4; ++r) {
      float bm = fmaxf(fmaxf(s[0][r], s[1][r]), fmaxf(s[2][r], s[3][r]));
#pragma unroll
      for (int off = 1; off < 16; off <<= 1) bm = fmaxf(bm, __shfl_xor(bm, off));
      const float mn = fmaxf(mr[r], bm);
      al[r] = __expf(mr[r] - mn);
      mr[r] = mn;
      float rs = 0.f;
#pragma unroll
      for (int t = 0; t < 4; ++t) { const float p = __expf(s[t][r] - mn); s[t][r] = p; rs += p; }
#pragma unroll
      for (int off = 1; off < 16; off <<= 1) rs += __shfl_xor(rs, off);
      lr[r] = lr[r] * al[r] + rs;
    }
#pragma unroll
    for (int t = 0; t < 4; ++t)
#pragma unroll
      for (int r = 0; r < 4; ++r) acc[t][r] *= al[r];

    // P -> LDS (transpose to A-fragment layout)
#pragma unroll
    for (int t = 0; t < 4; ++t)
#pragma unroll
      for (int r = 0; r < 4; ++r)
        Ps[w][(lh * 4 + r) * 72 + t * 16 + ln15] = f2bf(s[t][r]);
    __syncthreads();

    // O += P V
    bf16x8 ap[2];
#pragma unroll
    for (int ch = 0; ch < 2; ++ch)
      ap[ch] = *reinterpret_cast<const bf16x8*>(&Ps[w][ln15 * 72 + ch * 32 + lh * 8]);
#pragma unroll
    for (int dt = 0; dt < 4; ++dt) {
#pragma unroll
      for (int ch = 0; ch < 2; ++ch) {
        bf16x8 bv = *reinterpret_cast<const bf16x8*>(&Vs[(dt * 16 + ln15) * 64 + ch * 32 + lh * 8]);
        acc[dt] = __builtin_amdgcn_mfma_f32_16x16x32_bf16(ap[ch], bv, acc[dt], 0, 0, 0);
      }
    }
    __syncthreads();
  }

  const int qrow = qb * 64 + w * 16 + lh * 4;
#pragma unroll
  for (int dt = 0; dt < 4; ++dt)
#pragma unroll
    for (int r = 0; r < 4; ++r) {
      const float v = acc[dt][r] / lr[r];
      O[((size_t)b * SEQ + qrow + r) * DMODEL + h * 64 + dt * 16 + ln15] = f2bf(v);
    }
}

extern "C" void kernel_launch(void* const* d_in, const int* in_sizes, int n_in,
                              void* d_out, int out_size, void* d_ws, size_t ws_size,
                              hipStream_t stream) {
  const float* x      = (const float*)d_in[0];
  const float* qkv_w  = (const float*)d_in[1];
  const float* proj_w = (const float*)d_in[2];
  const float* proj_b = (const float*)d_in[3];
  float* out = (float*)d_out;

  char* ws = (char*)d_ws;
  const size_t SZ_XB  = (size_t)MTOT * DMODEL * 2;   // x bf16; reused as attn-out bf16
  const size_t SZ_WQT = (size_t)NQKV * DMODEL * 2;
  const size_t SZ_WPT = (size_t)DMODEL * DMODEL * 2;
  const size_t SZ_QKV = (size_t)BB * NHEAD * SEQ * HDIM * 2;
  unsigned short* Xb  = (unsigned short*)ws;
  unsigned short* WqT = (unsigned short*)(ws + SZ_XB);
  unsigned short* WpT = (unsigned short*)(ws + SZ_XB + SZ_WQT);
  unsigned short* Qd  = (unsigned short*)(ws + SZ_XB + SZ_WQT + SZ_WPT);
  unsigned short* Kd  = (unsigned short*)(ws + SZ_XB + SZ_WQT + SZ_WPT + SZ_QKV);
  unsigned short* Vt  = (unsigned short*)(ws + SZ_XB + SZ_WQT + SZ_WPT + 2 * SZ_QKV);
  if (ws_size < SZ_XB + SZ_WQT + SZ_WPT + 3 * SZ_QKV) return;

  // 1) x -> bf16
  k_cvt_bf16<<<2048, 256, 0, stream>>>((const float4*)x, (ushort4*)Xb, MTOT * DMODEL / 4);
  // 2) weight transposes (f32 -> bf16, B^T layout)
  k_transpose_bf16<<<dim3(NQKV / 32, DMODEL / 32), 256, 0, stream>>>(qkv_w, WqT, DMODEL, NQKV);
  k_transpose_bf16<<<dim3(DMODEL / 32, DMODEL / 32), 256, 0, stream>>>(proj_w, WpT, DMODEL, DMODEL);
  // 3) QKV projection, scattered to per-head Q, K, V^T
  k_gemm_bt<1><<<dim3(NQKV / 128, MTOT / 128), 256, 0, stream>>>(
      Xb, WqT, MTOT, NQKV, DMODEL, nullptr, nullptr, Qd, Kd, Vt);
  // 4) fused attention -> Oattn (reuses Xb region)
  k_attn<<<BB * NHEAD * (SEQ / 64), 256, 0, stream>>>(Qd, Kd, Vt, Xb);
  // 5) output projection + bias -> f32 out
  k_gemm_bt<0><<<dim3(DMODEL / 128, MTOT / 128), 256, 0, stream>>>(
      Xb, WpT, MTOT, DMODEL, DMODEL, out, proj_b, nullptr, nullptr, nullptr);
}

// Round 2
// 325.181 us; speedup vs baseline: 1.1540x; 1.1540x over previous
//
#include <hip/hip_runtime.h>
#include <cstdint>
#include <cstddef>

typedef float f32x4 __attribute__((ext_vector_type(4)));
typedef __bf16 bf16x8 __attribute__((ext_vector_type(8)));

#define BB 16
#define SEQ 1024
#define DMODEL 768
#define NHEAD 12
#define HDIM 64
#define MTOT (BB * SEQ)
#define NQKV (3 * DMODEL)

static __device__ __forceinline__ unsigned short f2bf(float f) {
  unsigned int u = __builtin_bit_cast(unsigned int, f);
  u += 0x7fffu + ((u >> 16) & 1u);
  return (unsigned short)(u >> 16);
}

static __device__ __forceinline__ void gload_lds16(const void* g, void* l) {
  __builtin_amdgcn_global_load_lds((__attribute__((address_space(1))) void*)g,
                                   (__attribute__((address_space(3))) void*)l,
                                   16, 0, 0);
}

// ---- prep: f32 -> bf16 convert (vectorized) ----
__global__ void k_cvt_bf16(const float4* __restrict__ in, ushort4* __restrict__ out, int n4) {
  int stride = gridDim.x * blockDim.x;
  for (int i = blockIdx.x * blockDim.x + threadIdx.x; i < n4; i += stride) {
    float4 v = in[i];
    ushort4 o;
    o.x = f2bf(v.x); o.y = f2bf(v.y); o.z = f2bf(v.z); o.w = f2bf(v.w);
    out[i] = o;
  }
}

// ---- prep: transpose f32 [R][C] -> bf16 [C][R] ----
__global__ void k_transpose_bf16(const float* __restrict__ in, unsigned short* __restrict__ out,
                                 int R, int C) {
  __shared__ float tile[32][33];
  int tx = threadIdx.x & 31, ty = threadIdx.x >> 5;
  int c0 = blockIdx.x * 32, r0 = blockIdx.y * 32;
#pragma unroll
  for (int i = 0; i < 4; ++i)
    tile[ty + i * 8][tx] = in[(size_t)(r0 + ty + i * 8) * C + c0 + tx];
  __syncthreads();
#pragma unroll
  for (int i = 0; i < 4; ++i)
    out[(size_t)(c0 + ty + i * 8) * R + r0 + tx] = f2bf(tile[tx][ty + i * 8]);
}

// ---- GEMM C[M,N] = A[M,K] * Bt[N,K]^T, bf16 in, f32 accum ----
// MODE 0: outF = C + bias (f32). MODE 1: scatter to Q (pre-scaled), K, V^T.
template <int MODE>
__global__ __launch_bounds__(256) void k_gemm_bt(
    const unsigned short* __restrict__ A, const unsigned short* __restrict__ Bt,
    int M, int N, int K,
    float* __restrict__ outF, const float* __restrict__ bias,
    unsigned short* __restrict__ Qd, unsigned short* __restrict__ Kd,
    unsigned short* __restrict__ Vt) {
  __shared__ __align__(16) unsigned short As[128 * 32];
  __shared__ __align__(16) unsigned short Bs[128 * 32];
  const int tid = threadIdx.x;
  const int lane = tid & 63, wid = tid >> 6;
  const int ln15 = lane & 15, lh = lane >> 4;
  const int wr = wid >> 1, wc = wid & 1;
  const int m0 = blockIdx.y * 128, n0 = blockIdx.x * 128;
  f32x4 acc[4][4] = {};
  const int nk = K >> 5;
  const int srow = lane >> 2;      // row within 16-row chunk
  const int skb = (lane & 3) * 8;  // k element offset within 32

  for (int kt = 0; kt < nk; ++kt) {
    const int k0 = kt * 32;
#pragma unroll
    for (int c2 = 0; c2 < 2; ++c2) {
      const int c = wid * 2 + c2;
      const int row = c * 16 + srow;
      gload_lds16(A + (size_t)(m0 + row) * K + k0 + skb, &As[c * 512]);
      gload_lds16(Bt + (size_t)(n0 + row) * K + k0 + skb, &Bs[c * 512]);
    }
    __syncthreads();
    bf16x8 af[4], bfv[4];
#pragma unroll
    for (int t = 0; t < 4; ++t) {
      af[t]  = *reinterpret_cast<const bf16x8*>(&As[(wr * 64 + t * 16 + ln15) * 32 + lh * 8]);
      bfv[t] = *reinterpret_cast<const bf16x8*>(&Bs[(wc * 64 + t * 16 + ln15) * 32 + lh * 8]);
    }
#pragma unroll
    for (int mt = 0; mt < 4; ++mt)
#pragma unroll
      for (int nt = 0; nt < 4; ++nt)
        acc[mt][nt] = __builtin_amdgcn_mfma_f32_16x16x32_bf16(af[mt], bfv[nt], acc[mt][nt], 0, 0, 0);
    __syncthreads();
  }

#pragma unroll
  for (int mt = 0; mt < 4; ++mt) {
#pragma unroll
    for (int nt = 0; nt < 4; ++nt) {
#pragma unroll
      for (int r = 0; r < 4; ++r) {
        const int m = m0 + wr * 64 + mt * 16 + lh * 4 + r;
        const int n = n0 + wc * 64 + nt * 16 + ln15;
        const float v = acc[mt][nt][r];
        if (MODE == 0) {
          outF[(size_t)m * N + n] = v + bias[n];
        } else {
          const int which = n / DMODEL;
          const int rr = n - which * DMODEL;
          const int h = rr >> 6, d = rr & 63;
          const int b = m >> 10, nr = m & 1023;
          const size_t bh = (size_t)(b * NHEAD + h);
          if (which == 0)      Qd[(bh * SEQ + nr) * HDIM + d] = f2bf(v * 0.125f);  // fold softmax scale
          else if (which == 1) Kd[(bh * SEQ + nr) * HDIM + d] = f2bf(v);
          else                 Vt[(bh * HDIM + d) * SEQ + nr] = f2bf(v);
        }
      }
    }
  }
}

// ---- fused flash-style attention: per block = (b, h, 64 q-rows); 4 waves x 16 rows ----
// Ks/Vs are stored XOR-swizzled: physical col = logical col ^ ((row&7)<<3) elements.
// global_load_lds writes linearly, so the SOURCE address carries the inverse permutation
// (same involution) and reads apply the XOR (rule 21: both-sides-or-neither).
__global__ __launch_bounds__(256) void k_attn(
    const unsigned short* __restrict__ Qd, const unsigned short* __restrict__ Kd,
    const unsigned short* __restrict__ Vt, unsigned short* __restrict__ O) {
  __shared__ __align__(16) unsigned short Ks[64 * 64];      // [kpos][d], swizzled
  __shared__ __align__(16) unsigned short Vs[64 * 64];      // [d][kpos], swizzled
  __shared__ __align__(16) unsigned short Ps[4][16 * 72];   // per-wave P [q][kpos], stride 72
  const int tid = threadIdx.x;
  const int lane = tid & 63, w = tid >> 6;
  const int ln15 = lane & 15, lh = lane >> 4;
  const int bid = blockIdx.x;
  const int qb = bid & 15;
  const int h = (bid >> 4) % NHEAD;
  const int b = bid / (16 * NHEAD);
  const size_t bh = (size_t)(b * NHEAD + h);
  const unsigned short* Qbase = Qd + (bh * SEQ + (size_t)qb * 64 + w * 16) * HDIM;
  const unsigned short* Kbase = Kd + bh * SEQ * HDIM;
  const unsigned short* Vbase = Vt + bh * HDIM * SEQ;

  // staging source swizzle: lane covers row (lane>>3) of an 8-row chunk,
  // within-row 16B block index = (lane&7) ^ (lane>>3)
  const int srow = lane >> 3;
  const int sblk = ((lane & 7) ^ srow) * 8;
  // read-side swizzle for 16-lane groups: element offset ^= (row&7)<<3, row = *+ln15
  const int swz = (ln15 & 7) << 3;

  bf16x8 aq[2];
#pragma unroll
  for (int ch = 0; ch < 2; ++ch)
    aq[ch] = *reinterpret_cast<const bf16x8*>(Qbase + (size_t)ln15 * HDIM + ch * 32 + lh * 8);

  f32x4 acc[4] = {};
  float mr[4], lr[4];
#pragma unroll
  for (int r = 0; r < 4; ++r) { mr[r] = -1e30f; lr[r] = 0.f; }

  for (int kb = 0; kb < SEQ / 64; ++kb) {
    const unsigned short* Kt = Kbase + (size_t)kb * 64 * HDIM;  // contiguous 64x64 tile
#pragma unroll
    for (int c2 = 0; c2 < 2; ++c2) {
      const int c = w * 2 + c2;
      const int row = c * 8 + srow;
      gload_lds16(Kt + (size_t)row * 64 + sblk, &Ks[c * 512]);
      gload_lds16(Vbase + (size_t)row * SEQ + kb * 64 + sblk, &Vs[c * 512]);
    }
    __syncthreads();

    // S = (Q*scale) K^T   (scale pre-folded into Q)
    f32x4 s[4] = {};
    __builtin_amdgcn_s_setprio(1);
#pragma unroll
    for (int t = 0; t < 4; ++t) {
#pragma unroll
      for (int ch = 0; ch < 2; ++ch) {
        bf16x8 bk = *reinterpret_cast<const bf16x8*>(
            &Ks[(t * 16 + ln15) * 64 + ((ch * 32 + lh * 8) ^ swz)]);
        s[t] = __builtin_amdgcn_mfma_f32_16x16x32_bf16(aq[ch], bk, s[t], 0, 0, 0);
      }
    }
    __builtin_amdgcn_s_setprio(0);

    // online softmax (rows live on reg index; row-reduce across 16 lanes of group)
    float al[4];
#pragma unroll
    for (int r = 0; r < 4; ++r) {
      float bm = fmaxf(fmaxf(s[0][r], s[1][r]), fmaxf(s[2][r], s[3][r]));
#pragma unroll
      for (int off = 1; off < 16; off <<= 1) bm = fmaxf(bm, __shfl_xor(bm, off));
      const float mn = fmaxf(mr[r], bm);
      al[r] = __expf(mr[r] - mn);
      mr[r] = mn;
      float rs = 0.f;
#pragma unroll
      for (int t = 0; t < 4; ++t) { const float p = __expf(s[t][r] - mn); s[t][r] = p; rs += p; }
#pragma unroll
      for (int off = 1; off < 16; off <<= 1) rs += __shfl_xor(rs, off);
      lr[r] = lr[r] * al[r] + rs;
    }
#pragma unroll
    for (int t = 0; t < 4; ++t)
#pragma unroll
      for (int r = 0; r < 4; ++r) acc[t][r] *= al[r];

    // P -> LDS (transpose to A-fragment layout)
#pragma unroll
    for (int t = 0; t < 4; ++t)
#pragma unroll
      for (int r = 0; r < 4; ++r)
        Ps[w][(lh * 4 + r) * 72 + t * 16 + ln15] = f2bf(s[t][r]);
    __syncthreads();

    // O += P V
    bf16x8 ap[2];
#pragma unroll
    for (int ch = 0; ch < 2; ++ch)
      ap[ch] = *reinterpret_cast<const bf16x8*>(&Ps[w][ln15 * 72 + ch * 32 + lh * 8]);
    __builtin_amdgcn_s_setprio(1);
#pragma unroll
    for (int dt = 0; dt < 4; ++dt) {
#pragma unroll
      for (int ch = 0; ch < 2; ++ch) {
        bf16x8 bv = *reinterpret_cast<const bf16x8*>(
            &Vs[(dt * 16 + ln15) * 64 + ((ch * 32 + lh * 8) ^ swz)]);
        acc[dt] = __builtin_amdgcn_mfma_f32_16x16x32_bf16(ap[ch], bv, acc[dt], 0, 0, 0);
      }
    }
    __builtin_amdgcn_s_setprio(0);
    __syncthreads();
  }

  const int qrow = qb * 64 + w * 16 + lh * 4;
#pragma unroll
  for (int dt = 0; dt < 4; ++dt)
#pragma unroll
    for (int r = 0; r < 4; ++r) {
      const float v = acc[dt][r] / lr[r];
      O[((size_t)b * SEQ + qrow + r) * DMODEL + h * 64 + dt * 16 + ln15] = f2bf(v);
    }
}

extern "C" void kernel_launch(void* const* d_in, const int* in_sizes, int n_in,
                              void* d_out, int out_size, void* d_ws, size_t ws_size,
                              hipStream_t stream) {
  const float* x      = (const float*)d_in[0];
  const float* qkv_w  = (const float*)d_in[1];
  const float* proj_w = (const float*)d_in[2];
  const float* proj_b = (const float*)d_in[3];
  float* out = (float*)d_out;

  char* ws = (char*)d_ws;
  const size_t SZ_XB  = (size_t)MTOT * DMODEL * 2;   // x bf16; reused as attn-out bf16
  const size_t SZ_WQT = (size_t)NQKV * DMODEL * 2;
  const size_t SZ_WPT = (size_t)DMODEL * DMODEL * 2;
  const size_t SZ_QKV = (size_t)BB * NHEAD * SEQ * HDIM * 2;
  unsigned short* Xb  = (unsigned short*)ws;
  unsigned short* WqT = (unsigned short*)(ws + SZ_XB);
  unsigned short* WpT = (unsigned short*)(ws + SZ_XB + SZ_WQT);
  unsigned short* Qd  = (unsigned short*)(ws + SZ_XB + SZ_WQT + SZ_WPT);
  unsigned short* Kd  = (unsigned short*)(ws + SZ_XB + SZ_WQT + SZ_WPT + SZ_QKV);
  unsigned short* Vt  = (unsigned short*)(ws + SZ_XB + SZ_WQT + SZ_WPT + 2 * SZ_QKV);
  if (ws_size < SZ_XB + SZ_WQT + SZ_WPT + 3 * SZ_QKV) return;

  // 1) x -> bf16
  k_cvt_bf16<<<2048, 256, 0, stream>>>((const float4*)x, (ushort4*)Xb, MTOT * DMODEL / 4);
  // 2) weight transposes (f32 -> bf16, B^T layout)
  k_transpose_bf16<<<dim3(NQKV / 32, DMODEL / 32), 256, 0, stream>>>(qkv_w, WqT, DMODEL, NQKV);
  k_transpose_bf16<<<dim3(DMODEL / 32, DMODEL / 32), 256, 0, stream>>>(proj_w, WpT, DMODEL, DMODEL);
  // 3) QKV projection, scattered to per-head Q (pre-scaled), K, V^T
  k_gemm_bt<1><<<dim3(NQKV / 128, MTOT / 128), 256, 0, stream>>>(
      Xb, WqT, MTOT, NQKV, DMODEL, nullptr, nullptr, Qd, Kd, Vt);
  // 4) fused attention -> Oattn (reuses Xb region)
  k_attn<<<BB * NHEAD * (SEQ / 64), 256, 0, stream>>>(Qd, Kd, Vt, Xb);
  // 5) output projection + bias -> f32 out
  k_gemm_bt<0><<<dim3(DMODEL / 128, MTOT / 128), 256, 0, stream>>>(
      Xb, WpT, MTOT, DMODEL, DMODEL, out, proj_b, nullptr, nullptr, nullptr);
}

// Round 3
// 269.847 us; speedup vs baseline: 1.3906x; 1.2051x over previous
//
#include <hip/hip_runtime.h>
#include <cstdint>
#include <cstddef>

typedef float f32x4 __attribute__((ext_vector_type(4)));
typedef __bf16 bf16x8 __attribute__((ext_vector_type(8)));

#define BB 16
#define SEQ 1024
#define DMODEL 768
#define NHEAD 12
#define HDIM 64
#define MTOT (BB * SEQ)
#define NQKV (3 * DMODEL)
// 0.125 (hd^-0.5) * log2(e): QK^T then exp2 == exp(0.125 * qk)
#define QSCALE 0.18033688011112042f

static __device__ __forceinline__ unsigned short f2bf(float f) {
  unsigned int u = __builtin_bit_cast(unsigned int, f);
  u += 0x7fffu + ((u >> 16) & 1u);
  return (unsigned short)(u >> 16);
}

static __device__ __forceinline__ unsigned cvt_pk_bf16(float lo, float hi) {
  unsigned r;
  asm("v_cvt_pk_bf16_f32 %0, %1, %2" : "=v"(r) : "v"(lo), "v"(hi));
  return r;
}

static __device__ __forceinline__ void gload_lds16(const void* g, void* l) {
  __builtin_amdgcn_global_load_lds((__attribute__((address_space(1))) void*)g,
                                   (__attribute__((address_space(3))) void*)l,
                                   16, 0, 0);
}

// ---- prep: f32 -> bf16 convert (vectorized) ----
__global__ void k_cvt_bf16(const float4* __restrict__ in, ushort4* __restrict__ out, int n4) {
  int stride = gridDim.x * blockDim.x;
  for (int i = blockIdx.x * blockDim.x + threadIdx.x; i < n4; i += stride) {
    float4 v = in[i];
    ushort4 o;
    o.x = f2bf(v.x); o.y = f2bf(v.y); o.z = f2bf(v.z); o.w = f2bf(v.w);
    out[i] = o;
  }
}

// ---- prep: transpose f32 [R][C] -> bf16 [C][R] ----
__global__ void k_transpose_bf16(const float* __restrict__ in, unsigned short* __restrict__ out,
                                 int R, int C) {
  __shared__ float tile[32][33];
  int tx = threadIdx.x & 31, ty = threadIdx.x >> 5;
  int c0 = blockIdx.x * 32, r0 = blockIdx.y * 32;
#pragma unroll
  for (int i = 0; i < 4; ++i)
    tile[ty + i * 8][tx] = in[(size_t)(r0 + ty + i * 8) * C + c0 + tx];
  __syncthreads();
#pragma unroll
  for (int i = 0; i < 4; ++i)
    out[(size_t)(c0 + ty + i * 8) * R + r0 + tx] = f2bf(tile[tx][ty + i * 8]);
}

// ---- GEMM C[M,N] = A[M,K] * Bt[N,K]^T, bf16 in, f32 accum ----
// MODE 0: outF = C + bias (f32). MODE 1: scatter to Q (pre-scaled by QSCALE), K, V^T.
template <int MODE>
__global__ __launch_bounds__(256) void k_gemm_bt(
    const unsigned short* __restrict__ A, const unsigned short* __restrict__ Bt,
    int M, int N, int K,
    float* __restrict__ outF, const float* __restrict__ bias,
    unsigned short* __restrict__ Qd, unsigned short* __restrict__ Kd,
    unsigned short* __restrict__ Vt) {
  __shared__ __align__(16) unsigned short As[128 * 32];
  __shared__ __align__(16) unsigned short Bs[128 * 32];
  const int tid = threadIdx.x;
  const int lane = tid & 63, wid = tid >> 6;
  const int ln15 = lane & 15, lh = lane >> 4;
  const int wr = wid >> 1, wc = wid & 1;
  const int m0 = blockIdx.y * 128, n0 = blockIdx.x * 128;
  f32x4 acc[4][4] = {};
  const int nk = K >> 5;
  const int srow = lane >> 2;      // row within 16-row chunk
  const int skb = (lane & 3) * 8;  // k element offset within 32

  for (int kt = 0; kt < nk; ++kt) {
    const int k0 = kt * 32;
#pragma unroll
    for (int c2 = 0; c2 < 2; ++c2) {
      const int c = wid * 2 + c2;
      const int row = c * 16 + srow;
      gload_lds16(A + (size_t)(m0 + row) * K + k0 + skb, &As[c * 512]);
      gload_lds16(Bt + (size_t)(n0 + row) * K + k0 + skb, &Bs[c * 512]);
    }
    __syncthreads();
    bf16x8 af[4], bfv[4];
#pragma unroll
    for (int t = 0; t < 4; ++t) {
      af[t]  = *reinterpret_cast<const bf16x8*>(&As[(wr * 64 + t * 16 + ln15) * 32 + lh * 8]);
      bfv[t] = *reinterpret_cast<const bf16x8*>(&Bs[(wc * 64 + t * 16 + ln15) * 32 + lh * 8]);
    }
#pragma unroll
    for (int mt = 0; mt < 4; ++mt)
#pragma unroll
      for (int nt = 0; nt < 4; ++nt)
        acc[mt][nt] = __builtin_amdgcn_mfma_f32_16x16x32_bf16(af[mt], bfv[nt], acc[mt][nt], 0, 0, 0);
    __syncthreads();
  }

#pragma unroll
  for (int mt = 0; mt < 4; ++mt) {
#pragma unroll
    for (int nt = 0; nt < 4; ++nt) {
#pragma unroll
      for (int r = 0; r < 4; ++r) {
        const int m = m0 + wr * 64 + mt * 16 + lh * 4 + r;
        const int n = n0 + wc * 64 + nt * 16 + ln15;
        const float v = acc[mt][nt][r];
        if (MODE == 0) {
          outF[(size_t)m * N + n] = v + bias[n];
        } else {
          const int which = n / DMODEL;
          const int rr = n - which * DMODEL;
          const int h = rr >> 6, d = rr & 63;
          const int b = m >> 10, nr = m & 1023;
          const size_t bh = (size_t)(b * NHEAD + h);
          if (which == 0)      Qd[(bh * SEQ + nr) * HDIM + d] = f2bf(v * QSCALE);
          else if (which == 1) Kd[(bh * SEQ + nr) * HDIM + d] = f2bf(v);
          else                 Vt[(bh * HDIM + d) * SEQ + nr] = f2bf(v);
        }
      }
    }
  }
}

// ---- fused flash attention, swapped-QK^T in-register softmax ----
// Per block = (b, h, 64 q-rows); 4 waves x 16 q-rows.
// S^T = mfma(A=K, B=Q): lane ln15 = q-row, regs (t, lh, r) = kpos -> row reduce is
// in-lane tree + 2 shuffles. P packed via v_cvt_pk_bf16_f32 and ds_write_b64.
// Ks/Vs XOR-swizzled (rule 21: linear LDS dest, inverse-swizzled global src, swz on read).
__global__ __launch_bounds__(256) void k_attn(
    const unsigned short* __restrict__ Qd, const unsigned short* __restrict__ Kd,
    const unsigned short* __restrict__ Vt, unsigned short* __restrict__ O) {
  __shared__ __align__(16) unsigned short Ks[64 * 64];      // [kpos][d], swizzled
  __shared__ __align__(16) unsigned short Vs[64 * 64];      // [d][kpos], swizzled
  __shared__ __align__(16) unsigned short Ps[4][16 * 72];   // per-wave P [q][kpos], stride 72
  const int tid = threadIdx.x;
  const int lane = tid & 63, w = tid >> 6;
  const int ln15 = lane & 15, lh = lane >> 4;
  const int bid = blockIdx.x;
  const int qb = bid & 15;
  const int h = (bid >> 4) % NHEAD;
  const int b = bid / (16 * NHEAD);
  const size_t bh = (size_t)(b * NHEAD + h);
  const unsigned short* Qbase = Qd + (bh * SEQ + (size_t)qb * 64 + w * 16) * HDIM;
  const unsigned short* Kbase = Kd + bh * SEQ * HDIM;
  const unsigned short* Vbase = Vt + bh * HDIM * SEQ;

  // staging source swizzle: lane covers row (lane>>3) of an 8-row chunk,
  // within-row 16B block index = (lane&7) ^ (lane>>3)
  const int srow = lane >> 3;
  const int sblk = ((lane & 7) ^ srow) * 8;
  // read-side swizzle: element offset ^= (row&7)<<3
  const int swz = (ln15 & 7) << 3;

  bf16x8 aq[2];  // B operand: lane ln15 = q-col, elems k = ch*32 + lh*8 ..
#pragma unroll
  for (int ch = 0; ch < 2; ++ch)
    aq[ch] = *reinterpret_cast<const bf16x8*>(Qbase + (size_t)ln15 * HDIM + ch * 32 + lh * 8);

  f32x4 acc[4] = {};
  float mr = -1e30f, lr = 0.f;  // per-lane running max/sum for q = ln15 (log2 domain)

  for (int kb = 0; kb < SEQ / 64; ++kb) {
    const unsigned short* Kt = Kbase + (size_t)kb * 64 * HDIM;
#pragma unroll
    for (int c2 = 0; c2 < 2; ++c2) {
      const int c = w * 2 + c2;
      const int row = c * 8 + srow;
      gload_lds16(Kt + (size_t)row * 64 + sblk, &Ks[c * 512]);
      gload_lds16(Vbase + (size_t)row * SEQ + kb * 64 + sblk, &Vs[c * 512]);
    }
    __syncthreads();

    // S^T = K Q^T  (Q pre-scaled by 0.125*log2e)
    f32x4 s[4] = {};
    __builtin_amdgcn_s_setprio(1);
#pragma unroll
    for (int t = 0; t < 4; ++t) {
#pragma unroll
      for (int ch = 0; ch < 2; ++ch) {
        bf16x8 bk = *reinterpret_cast<const bf16x8*>(
            &Ks[(t * 16 + ln15) * 64 + ((ch * 32 + lh * 8) ^ swz)]);
        s[t] = __builtin_amdgcn_mfma_f32_16x16x32_bf16(bk, aq[ch], s[t], 0, 0, 0);
      }
    }
    __builtin_amdgcn_s_setprio(0);

    // ---- in-register online softmax (lane owns 16 kpos values of q-row ln15) ----
    float bm;
    {
      const float a0 = fmaxf(fmaxf(s[0][0], s[0][1]), fmaxf(s[0][2], s[0][3]));
      const float a1 = fmaxf(fmaxf(s[1][0], s[1][1]), fmaxf(s[1][2], s[1][3]));
      const float a2 = fmaxf(fmaxf(s[2][0], s[2][1]), fmaxf(s[2][2], s[2][3]));
      const float a3 = fmaxf(fmaxf(s[3][0], s[3][1]), fmaxf(s[3][2], s[3][3]));
      bm = fmaxf(fmaxf(a0, a1), fmaxf(a2, a3));
    }
    bm = fmaxf(bm, __shfl_xor(bm, 16));
    bm = fmaxf(bm, __shfl_xor(bm, 32));
    // defer-max (T13): only rescale when max grew by > 8 (log2 domain -> 256x)
    const int grow = __any(bm > mr + 8.f);
    float al = 1.f;
    if (grow) {
      const float mn = fmaxf(mr, bm);
      al = __builtin_amdgcn_exp2f(mr - mn);
      mr = mn;
    }
#pragma unroll
    for (int t = 0; t < 4; ++t)
#pragma unroll
      for (int r = 0; r < 4; ++r) s[t][r] = __builtin_amdgcn_exp2f(s[t][r] - mr);
    float rs;
    {
      const float a0 = (s[0][0] + s[0][1]) + (s[0][2] + s[0][3]);
      const float a1 = (s[1][0] + s[1][1]) + (s[1][2] + s[1][3]);
      const float a2 = (s[2][0] + s[2][1]) + (s[2][2] + s[2][3]);
      const float a3 = (s[3][0] + s[3][1]) + (s[3][2] + s[3][3]);
      rs = (a0 + a1) + (a2 + a3);
    }
    rs += __shfl_xor(rs, 16);
    rs += __shfl_xor(rs, 32);
    lr = lr * al + rs;
    if (grow) {
      float alq[4];
#pragma unroll
      for (int r = 0; r < 4; ++r) alq[r] = __shfl(al, lh * 4 + r);
#pragma unroll
      for (int dt = 0; dt < 4; ++dt)
#pragma unroll
        for (int r = 0; r < 4; ++r) acc[dt][r] *= alq[r];
    }

    // pack P -> LDS: Ps[q=ln15][kpos = t*16 + lh*4 + r], b64 writes
#pragma unroll
    for (int t = 0; t < 4; ++t) {
      uint2 u;
      u.x = cvt_pk_bf16(s[t][0], s[t][1]);
      u.y = cvt_pk_bf16(s[t][2], s[t][3]);
      *reinterpret_cast<uint2*>(&Ps[w][ln15 * 72 + t * 16 + lh * 4]) = u;
    }

    // O += P V  (A = P rows q, B = V^T cols d)
    bf16x8 ap[2];
#pragma unroll
    for (int ch = 0; ch < 2; ++ch)
      ap[ch] = *reinterpret_cast<const bf16x8*>(&Ps[w][ln15 * 72 + ch * 32 + lh * 8]);
    __builtin_amdgcn_s_setprio(1);
#pragma unroll
    for (int dt = 0; dt < 4; ++dt) {
#pragma unroll
      for (int ch = 0; ch < 2; ++ch) {
        bf16x8 bv = *reinterpret_cast<const bf16x8*>(
            &Vs[(dt * 16 + ln15) * 64 + ((ch * 32 + lh * 8) ^ swz)]);
        acc[dt] = __builtin_amdgcn_mfma_f32_16x16x32_bf16(ap[ch], bv, acc[dt], 0, 0, 0);
      }
    }
    __builtin_amdgcn_s_setprio(0);
    __syncthreads();
  }

  float lrq[4];
#pragma unroll
  for (int r = 0; r < 4; ++r) lrq[r] = 1.0f / __shfl(lr, lh * 4 + r);
  const int qrow = qb * 64 + w * 16 + lh * 4;
#pragma unroll
  for (int dt = 0; dt < 4; ++dt)
#pragma unroll
    for (int r = 0; r < 4; ++r)
      O[((size_t)b * SEQ + qrow + r) * DMODEL + h * 64 + dt * 16 + ln15] = f2bf(acc[dt][r] * lrq[r]);
}

extern "C" void kernel_launch(void* const* d_in, const int* in_sizes, int n_in,
                              void* d_out, int out_size, void* d_ws, size_t ws_size,
                              hipStream_t stream) {
  const float* x      = (const float*)d_in[0];
  const float* qkv_w  = (const float*)d_in[1];
  const float* proj_w = (const float*)d_in[2];
  const float* proj_b = (const float*)d_in[3];
  float* out = (float*)d_out;

  char* ws = (char*)d_ws;
  const size_t SZ_XB  = (size_t)MTOT * DMODEL * 2;   // x bf16; reused as attn-out bf16
  const size_t SZ_WQT = (size_t)NQKV * DMODEL * 2;
  const size_t SZ_WPT = (size_t)DMODEL * DMODEL * 2;
  const size_t SZ_QKV = (size_t)BB * NHEAD * SEQ * HDIM * 2;
  unsigned short* Xb  = (unsigned short*)ws;
  unsigned short* WqT = (unsigned short*)(ws + SZ_XB);
  unsigned short* WpT = (unsigned short*)(ws + SZ_XB + SZ_WQT);
  unsigned short* Qd  = (unsigned short*)(ws + SZ_XB + SZ_WQT + SZ_WPT);
  unsigned short* Kd  = (unsigned short*)(ws + SZ_XB + SZ_WQT + SZ_WPT + SZ_QKV);
  unsigned short* Vt  = (unsigned short*)(ws + SZ_XB + SZ_WQT + SZ_WPT + 2 * SZ_QKV);
  if (ws_size < SZ_XB + SZ_WQT + SZ_WPT + 3 * SZ_QKV) return;

  // 1) x -> bf16
  k_cvt_bf16<<<2048, 256, 0, stream>>>((const float4*)x, (ushort4*)Xb, MTOT * DMODEL / 4);
  // 2) weight transposes (f32 -> bf16, B^T layout)
  k_transpose_bf16<<<dim3(NQKV / 32, DMODEL / 32), 256, 0, stream>>>(qkv_w, WqT, DMODEL, NQKV);
  k_transpose_bf16<<<dim3(DMODEL / 32, DMODEL / 32), 256, 0, stream>>>(proj_w, WpT, DMODEL, DMODEL);
  // 3) QKV projection, scattered to per-head Q (pre-scaled), K, V^T
  k_gemm_bt<1><<<dim3(NQKV / 128, MTOT / 128), 256, 0, stream>>>(
      Xb, WqT, MTOT, NQKV, DMODEL, nullptr, nullptr, Qd, Kd, Vt);
  // 4) fused attention -> Oattn (reuses Xb region)
  k_attn<<<BB * NHEAD * (SEQ / 64), 256, 0, stream>>>(Qd, Kd, Vt, Xb);
  // 5) output projection + bias -> f32 out
  k_gemm_bt<0><<<dim3(DMODEL / 128, MTOT / 128), 256, 0, stream>>>(
      Xb, WpT, MTOT, DMODEL, DMODEL, out, proj_b, nullptr, nullptr, nullptr);
}

// Round 4
// 240.323 us; speedup vs baseline: 1.5615x; 1.1229x over previous
//
#include <hip/hip_runtime.h>
#include <cstdint>
#include <cstddef>

typedef float f32x4 __attribute__((ext_vector_type(4)));
typedef __bf16 bf16x8 __attribute__((ext_vector_type(8)));

#define BB 16
#define SEQ 1024
#define DMODEL 768
#define NHEAD 12
#define HDIM 64
#define MTOT (BB * SEQ)
#define NQKV (3 * DMODEL)
// 0.125 (hd^-0.5) * log2(e): QK^T then exp2 == exp(0.125 * qk)
#define QSCALE 0.18033688011112042f

static __device__ __forceinline__ unsigned short f2bf(float f) {
  unsigned int u = __builtin_bit_cast(unsigned int, f);
  u += 0x7fffu + ((u >> 16) & 1u);
  return (unsigned short)(u >> 16);
}

static __device__ __forceinline__ unsigned cvt_pk_bf16(float lo, float hi) {
  unsigned r;
  asm("v_cvt_pk_bf16_f32 %0, %1, %2" : "=v"(r) : "v"(lo), "v"(hi));
  return r;
}

static __device__ __forceinline__ void gload_lds16(const void* g, void* l) {
  __builtin_amdgcn_global_load_lds((__attribute__((address_space(1))) void*)g,
                                   (__attribute__((address_space(3))) void*)l,
                                   16, 0, 0);
}

// ---- prep: f32 -> bf16 convert (vectorized) ----
__global__ void k_cvt_bf16(const float4* __restrict__ in, ushort4* __restrict__ out, int n4) {
  int stride = gridDim.x * blockDim.x;
  for (int i = blockIdx.x * blockDim.x + threadIdx.x; i < n4; i += stride) {
    float4 v = in[i];
    ushort4 o;
    o.x = f2bf(v.x); o.y = f2bf(v.y); o.z = f2bf(v.z); o.w = f2bf(v.w);
    out[i] = o;
  }
}

// ---- prep: transpose f32 [R][C] -> bf16 [C][R] ----
__global__ void k_transpose_bf16(const float* __restrict__ in, unsigned short* __restrict__ out,
                                 int R, int C) {
  __shared__ float tile[32][33];
  int tx = threadIdx.x & 31, ty = threadIdx.x >> 5;
  int c0 = blockIdx.x * 32, r0 = blockIdx.y * 32;
#pragma unroll
  for (int i = 0; i < 4; ++i)
    tile[ty + i * 8][tx] = in[(size_t)(r0 + ty + i * 8) * C + c0 + tx];
  __syncthreads();
#pragma unroll
  for (int i = 0; i < 4; ++i)
    out[(size_t)(c0 + ty + i * 8) * R + r0 + tx] = f2bf(tile[tx][ty + i * 8]);
}

// ---- GEMM C[M,N] = A[M,K] * Bt[N,K]^T, bf16 in, f32 accum ----
// Block tile 128(m) x 256(n), BK=64, 4 waves each computing 64x128 (acc 4x8).
// LDS XOR-swizzled (T2, rule 21): linear LDS dest for global_load_lds, the global
// SOURCE carries the involution (16B block ^= row&7), reads XOR the same bits.
// MODE 0: outF = C + bias (f32). MODE 1: scatter to Q (pre-scaled), K, V^T.
template <int MODE>
__global__ __launch_bounds__(256, 2) void k_gemm_bt(
    const unsigned short* __restrict__ A, const unsigned short* __restrict__ Bt,
    int M, int N, int K,
    float* __restrict__ outF, const float* __restrict__ bias,
    unsigned short* __restrict__ Qd, unsigned short* __restrict__ Kd,
    unsigned short* __restrict__ Vt) {
  __shared__ __align__(16) unsigned short As[128 * 64];  // 16 KB
  __shared__ __align__(16) unsigned short Bs[256 * 64];  // 32 KB
  const int tid = threadIdx.x;
  const int lane = tid & 63, wid = tid >> 6;
  const int ln15 = lane & 15, lh = lane >> 4;
  const int wr = wid >> 1, wc = wid & 1;
  const int m0 = blockIdx.x * 128, n0 = blockIdx.y * 256;
  f32x4 acc[4][8] = {};
  // staging: 1KB chunk = 8 rows; lane covers row (lane>>3), 16B block ((lane&7)^(lane>>3))
  const int srow = lane >> 3;
  const int sblk = ((lane & 7) ^ srow) * 8;
  // read-side swizzle: element offset ^= (row&7)<<3
  const int swz = (ln15 & 7) << 3;
  const int nk = K >> 6;

  for (int kt = 0; kt < nk; ++kt) {
    const int k0 = kt * 64;
#pragma unroll
    for (int c = 0; c < 4; ++c) {  // A: 16 chunks, wave takes 4
      const int ch = wid * 4 + c;
      const int row = ch * 8 + srow;
      gload_lds16(A + (size_t)(m0 + row) * K + k0 + sblk, &As[ch * 512]);
    }
#pragma unroll
    for (int c = 0; c < 8; ++c) {  // B: 32 chunks, wave takes 8
      const int ch = wid * 8 + c;
      const int row = ch * 8 + srow;
      gload_lds16(Bt + (size_t)(n0 + row) * K + k0 + sblk, &Bs[ch * 512]);
    }
    __syncthreads();
#pragma unroll
    for (int kk = 0; kk < 2; ++kk) {
      const int kc = kk * 32 + lh * 8;
      bf16x8 af[4], bfv[8];
#pragma unroll
      for (int mt = 0; mt < 4; ++mt)
        af[mt] = *reinterpret_cast<const bf16x8*>(
            &As[(wr * 64 + mt * 16 + ln15) * 64 + (kc ^ swz)]);
#pragma unroll
      for (int nt = 0; nt < 8; ++nt)
        bfv[nt] = *reinterpret_cast<const bf16x8*>(
            &Bs[(wc * 128 + nt * 16 + ln15) * 64 + (kc ^ swz)]);
#pragma unroll
      for (int mt = 0; mt < 4; ++mt)
#pragma unroll
        for (int nt = 0; nt < 8; ++nt)
          acc[mt][nt] = __builtin_amdgcn_mfma_f32_16x16x32_bf16(af[mt], bfv[nt], acc[mt][nt], 0, 0, 0);
    }
    __syncthreads();
  }

#pragma unroll
  for (int mt = 0; mt < 4; ++mt) {
#pragma unroll
    for (int nt = 0; nt < 8; ++nt) {
#pragma unroll
      for (int r = 0; r < 4; ++r) {
        const int m = m0 + wr * 64 + mt * 16 + lh * 4 + r;
        const int n = n0 + wc * 128 + nt * 16 + ln15;
        const float v = acc[mt][nt][r];
        if (MODE == 0) {
          outF[(size_t)m * N + n] = v + bias[n];
        } else {
          const int which = n / DMODEL;
          const int rr = n - which * DMODEL;
          const int h = rr >> 6, d = rr & 63;
          const int b = m >> 10, nr = m & 1023;
          const size_t bh = (size_t)(b * NHEAD + h);
          if (which == 0)      Qd[(bh * SEQ + nr) * HDIM + d] = f2bf(v * QSCALE);
          else if (which == 1) Kd[(bh * SEQ + nr) * HDIM + d] = f2bf(v);
          else                 Vt[(bh * HDIM + d) * SEQ + nr] = f2bf(v);
        }
      }
    }
  }
}

// ---- fused flash attention, swapped-QK^T in-register softmax ----
__global__ __launch_bounds__(256) void k_attn(
    const unsigned short* __restrict__ Qd, const unsigned short* __restrict__ Kd,
    const unsigned short* __restrict__ Vt, unsigned short* __restrict__ O) {
  __shared__ __align__(16) unsigned short Ks[64 * 64];      // [kpos][d], swizzled
  __shared__ __align__(16) unsigned short Vs[64 * 64];      // [d][kpos], swizzled
  __shared__ __align__(16) unsigned short Ps[4][16 * 72];   // per-wave P [q][kpos], stride 72
  const int tid = threadIdx.x;
  const int lane = tid & 63, w = tid >> 6;
  const int ln15 = lane & 15, lh = lane >> 4;
  const int bid = blockIdx.x;
  const int qb = bid & 15;
  const int h = (bid >> 4) % NHEAD;
  const int b = bid / (16 * NHEAD);
  const size_t bh = (size_t)(b * NHEAD + h);
  const unsigned short* Qbase = Qd + (bh * SEQ + (size_t)qb * 64 + w * 16) * HDIM;
  const unsigned short* Kbase = Kd + bh * SEQ * HDIM;
  const unsigned short* Vbase = Vt + bh * HDIM * SEQ;

  const int srow = lane >> 3;
  const int sblk = ((lane & 7) ^ srow) * 8;
  const int swz = (ln15 & 7) << 3;

  bf16x8 aq[2];
#pragma unroll
  for (int ch = 0; ch < 2; ++ch)
    aq[ch] = *reinterpret_cast<const bf16x8*>(Qbase + (size_t)ln15 * HDIM + ch * 32 + lh * 8);

  f32x4 acc[4] = {};
  float mr = -1e30f, lr = 0.f;

  for (int kb = 0; kb < SEQ / 64; ++kb) {
    const unsigned short* Kt = Kbase + (size_t)kb * 64 * HDIM;
#pragma unroll
    for (int c2 = 0; c2 < 2; ++c2) {
      const int c = w * 2 + c2;
      const int row = c * 8 + srow;
      gload_lds16(Kt + (size_t)row * 64 + sblk, &Ks[c * 512]);
      gload_lds16(Vbase + (size_t)row * SEQ + kb * 64 + sblk, &Vs[c * 512]);
    }
    __syncthreads();

    f32x4 s[4] = {};
    __builtin_amdgcn_s_setprio(1);
#pragma unroll
    for (int t = 0; t < 4; ++t) {
#pragma unroll
      for (int ch = 0; ch < 2; ++ch) {
        bf16x8 bk = *reinterpret_cast<const bf16x8*>(
            &Ks[(t * 16 + ln15) * 64 + ((ch * 32 + lh * 8) ^ swz)]);
        s[t] = __builtin_amdgcn_mfma_f32_16x16x32_bf16(bk, aq[ch], s[t], 0, 0, 0);
      }
    }
    __builtin_amdgcn_s_setprio(0);

    float bm;
    {
      const float a0 = fmaxf(fmaxf(s[0][0], s[0][1]), fmaxf(s[0][2], s[0][3]));
      const float a1 = fmaxf(fmaxf(s[1][0], s[1][1]), fmaxf(s[1][2], s[1][3]));
      const float a2 = fmaxf(fmaxf(s[2][0], s[2][1]), fmaxf(s[2][2], s[2][3]));
      const float a3 = fmaxf(fmaxf(s[3][0], s[3][1]), fmaxf(s[3][2], s[3][3]));
      bm = fmaxf(fmaxf(a0, a1), fmaxf(a2, a3));
    }
    bm = fmaxf(bm, __shfl_xor(bm, 16));
    bm = fmaxf(bm, __shfl_xor(bm, 32));
    const int grow = __any(bm > mr + 8.f);
    float al = 1.f;
    if (grow) {
      const float mn = fmaxf(mr, bm);
      al = __builtin_amdgcn_exp2f(mr - mn);
      mr = mn;
    }
#pragma unroll
    for (int t = 0; t < 4; ++t)
#pragma unroll
      for (int r = 0; r < 4; ++r) s[t][r] = __builtin_amdgcn_exp2f(s[t][r] - mr);
    float rs;
    {
      const float a0 = (s[0][0] + s[0][1]) + (s[0][2] + s[0][3]);
      const float a1 = (s[1][0] + s[1][1]) + (s[1][2] + s[1][3]);
      const float a2 = (s[2][0] + s[2][1]) + (s[2][2] + s[2][3]);
      const float a3 = (s[3][0] + s[3][1]) + (s[3][2] + s[3][3]);
      rs = (a0 + a1) + (a2 + a3);
    }
    rs += __shfl_xor(rs, 16);
    rs += __shfl_xor(rs, 32);
    lr = lr * al + rs;
    if (grow) {
      float alq[4];
#pragma unroll
      for (int r = 0; r < 4; ++r) alq[r] = __shfl(al, lh * 4 + r);
#pragma unroll
      for (int dt = 0; dt < 4; ++dt)
#pragma unroll
        for (int r = 0; r < 4; ++r) acc[dt][r] *= alq[r];
    }

#pragma unroll
    for (int t = 0; t < 4; ++t) {
      uint2 u;
      u.x = cvt_pk_bf16(s[t][0], s[t][1]);
      u.y = cvt_pk_bf16(s[t][2], s[t][3]);
      *reinterpret_cast<uint2*>(&Ps[w][ln15 * 72 + t * 16 + lh * 4]) = u;
    }

    bf16x8 ap[2];
#pragma unroll
    for (int ch = 0; ch < 2; ++ch)
      ap[ch] = *reinterpret_cast<const bf16x8*>(&Ps[w][ln15 * 72 + ch * 32 + lh * 8]);
    __builtin_amdgcn_s_setprio(1);
#pragma unroll
    for (int dt = 0; dt < 4; ++dt) {
#pragma unroll
      for (int ch = 0; ch < 2; ++ch) {
        bf16x8 bv = *reinterpret_cast<const bf16x8*>(
            &Vs[(dt * 16 + ln15) * 64 + ((ch * 32 + lh * 8) ^ swz)]);
        acc[dt] = __builtin_amdgcn_mfma_f32_16x16x32_bf16(ap[ch], bv, acc[dt], 0, 0, 0);
      }
    }
    __builtin_amdgcn_s_setprio(0);
    __syncthreads();
  }

  float lrq[4];
#pragma unroll
  for (int r = 0; r < 4; ++r) lrq[r] = 1.0f / __shfl(lr, lh * 4 + r);
  const int qrow = qb * 64 + w * 16 + lh * 4;
#pragma unroll
  for (int dt = 0; dt < 4; ++dt)
#pragma unroll
    for (int r = 0; r < 4; ++r)
      O[((size_t)b * SEQ + qrow + r) * DMODEL + h * 64 + dt * 16 + ln15] = f2bf(acc[dt][r] * lrq[r]);
}

extern "C" void kernel_launch(void* const* d_in, const int* in_sizes, int n_in,
                              void* d_out, int out_size, void* d_ws, size_t ws_size,
                              hipStream_t stream) {
  const float* x      = (const float*)d_in[0];
  const float* qkv_w  = (const float*)d_in[1];
  const float* proj_w = (const float*)d_in[2];
  const float* proj_b = (const float*)d_in[3];
  float* out = (float*)d_out;

  char* ws = (char*)d_ws;
  const size_t SZ_XB  = (size_t)MTOT * DMODEL * 2;   // x bf16; reused as attn-out bf16
  const size_t SZ_WQT = (size_t)NQKV * DMODEL * 2;
  const size_t SZ_WPT = (size_t)DMODEL * DMODEL * 2;
  const size_t SZ_QKV = (size_t)BB * NHEAD * SEQ * HDIM * 2;
  unsigned short* Xb  = (unsigned short*)ws;
  unsigned short* WqT = (unsigned short*)(ws + SZ_XB);
  unsigned short* WpT = (unsigned short*)(ws + SZ_XB + SZ_WQT);
  unsigned short* Qd  = (unsigned short*)(ws + SZ_XB + SZ_WQT + SZ_WPT);
  unsigned short* Kd  = (unsigned short*)(ws + SZ_XB + SZ_WQT + SZ_WPT + SZ_QKV);
  unsigned short* Vt  = (unsigned short*)(ws + SZ_XB + SZ_WQT + SZ_WPT + 2 * SZ_QKV);
  if (ws_size < SZ_XB + SZ_WQT + SZ_WPT + 3 * SZ_QKV) return;

  // 1) x -> bf16
  k_cvt_bf16<<<2048, 256, 0, stream>>>((const float4*)x, (ushort4*)Xb, MTOT * DMODEL / 4);
  // 2) weight transposes (f32 -> bf16, B^T layout)
  k_transpose_bf16<<<dim3(NQKV / 32, DMODEL / 32), 256, 0, stream>>>(qkv_w, WqT, DMODEL, NQKV);
  k_transpose_bf16<<<dim3(DMODEL / 32, DMODEL / 32), 256, 0, stream>>>(proj_w, WpT, DMODEL, DMODEL);
  // 3) QKV projection, scattered to per-head Q (pre-scaled), K, V^T
  //    grid m-major: consecutive blocks share the B n-panel (L2-resident)
  k_gemm_bt<1><<<dim3(MTOT / 128, NQKV / 256), 256, 0, stream>>>(
      Xb, WqT, MTOT, NQKV, DMODEL, nullptr, nullptr, Qd, Kd, Vt);
  // 4) fused attention -> Oattn (reuses Xb region)
  k_attn<<<BB * NHEAD * (SEQ / 64), 256, 0, stream>>>(Qd, Kd, Vt, Xb);
  // 5) output projection + bias -> f32 out
  k_gemm_bt<0><<<dim3(MTOT / 128, DMODEL / 256), 256, 0, stream>>>(
      Xb, WpT, MTOT, DMODEL, DMODEL, out, proj_b, nullptr, nullptr, nullptr);
}